// Round 4
// baseline (381.045 us; speedup 1.0000x reference)
//
#include <hip/hip_runtime.h>
#include <hip/hip_bf16.h>
#include <cstdint>
#include <cstddef>

#define N 4096
#define NN ((size_t)N * (size_t)N)

typedef int   int4v   __attribute__((ext_vector_type(4)));
typedef float float4v __attribute__((ext_vector_type(4)));

__device__ inline void async16(const void* g, void* lds) {
    __builtin_amdgcn_global_load_lds(
        (const __attribute__((address_space(1))) void*)g,
        (__attribute__((address_space(3))) void*)lds, 16, 0, 0);
}

// ---------------- kernel 1: FUSED mod + diag + build_A8 ----------------
// Each block owns the unordered tile pair {(I,J),(J,I)} (I<=J; blocks with I>J exit).
// mod is elementwise: hard = rint(sigmoid((logit(p)+logit(u))/tau)) == (p+u >= 1),
// m = fmaf(hard, -2o, o)  [proven bit-exact].  Each input element is read exactly
// once across the grid; out and the four i8 matrices are written once.  Diagonal
// entries d[x] = mod[x][x] are recomputed from inputs (64 scalar loads/block, L2-hot).
// All A-expressions keep the operand order of the previous build_A8:
//   A[r][c] = mod[r][c] + mod[c][r] - d[c]   (exact small integers).
__global__ void fused_mod_build(const float* __restrict__ ori,
                                const float* __restrict__ clp,
                                const float* __restrict__ uu,
                                float* __restrict__ out,
                                signed char* __restrict__ A,
                                signed char* __restrict__ AT,
                                signed char* __restrict__ Aa,
                                signed char* __restrict__ ATa,
                                double* __restrict__ accs) {
    const int I = blockIdx.x, J = blockIdx.y;
    if (I > J) return;
    __shared__ float sm1[32][33];   // sm1[i][j] = mod[bi+i][bj+j]
    __shared__ float sm2[32][33];   // sm2[j][i] = mod[bj+j][bi+i]
    __shared__ float dI[32], dJ[32];
    const int tx = threadIdx.x;     // 0..7
    const int ty = threadIdx.y;     // 0..31
    const int t = ty * 8 + tx;
    const int bi = I * 32, bj = J * 32;
    if (I == 0 && J == 0 && t < 2) accs[t] = 0.0;
    if (t < 64) {
        const int x = (t < 32) ? (bi + t) : (bj + (t - 32));
        const size_t off = (size_t)x * N + x;
        const float o = ori[off];
        const float hard = (clp[off] + uu[off] >= 1.0f) ? 1.0f : 0.0f;
        const float d = fmaf(hard, -2.0f * o, o);
        if (t < 32) dI[t] = d; else dJ[t - 32] = d;
    }
    // tile 1: rows bi..bi+31, cols bj..bj+31
    {
        const size_t off = (size_t)(bi + ty) * N + bj + tx * 4;
        const float4v o4 = *(const float4v*)(ori + off);
        const float4v p4 = *(const float4v*)(clp + off);
        const float4v u4 = *(const float4v*)(uu + off);
        float4v m;
        #pragma unroll
        for (int c = 0; c < 4; ++c) {
            const float hard = (p4[c] + u4[c] >= 1.0f) ? 1.0f : 0.0f;
            m[c] = fmaf(hard, -2.0f * o4[c], o4[c]);
            sm1[ty][tx * 4 + c] = m[c];
        }
        *(float4v*)(out + off) = m;
    }
    // tile 2: rows bj..bj+31, cols bi..bi+31 (same tile when I==J; redundant
    // recompute yields identical values, skip the duplicate out-write)
    {
        const size_t off = (size_t)(bj + ty) * N + bi + tx * 4;
        const float4v o4 = *(const float4v*)(ori + off);
        const float4v p4 = *(const float4v*)(clp + off);
        const float4v u4 = *(const float4v*)(uu + off);
        float4v m;
        #pragma unroll
        for (int c = 0; c < 4; ++c) {
            const float hard = (p4[c] + u4[c] >= 1.0f) ? 1.0f : 0.0f;
            m[c] = fmaf(hard, -2.0f * o4[c], o4[c]);
            sm2[ty][tx * 4 + c] = m[c];
        }
        if (I != J) *(float4v*)(out + off) = m;
    }
    __syncthreads();
    int pkA1 = 0, pkAa1 = 0, pkT1 = 0, pkTa1 = 0;
    int pkA2 = 0, pkAa2 = 0, pkT2 = 0, pkTa2 = 0;
    #pragma unroll
    for (int k = 0; k < 4; ++k) {
        const int c = tx * 4 + k;
        // A tile (I,J), row ty col c:  mod[bi+ty][bj+c] + mod[bj+c][bi+ty] - d[bj+c]
        const float a1 = sm1[ty][c] + sm2[c][ty] - dJ[c];
        const int v1 = (int)a1;  const int u1 = v1 < 0 ? -v1 : v1;
        pkA1  |= (v1 & 255) << (8 * k);
        pkAa1 |= (u1 & 255) << (8 * k);
        // AT tile (J,I), row ty col c: A[bi+c][bj+ty] = mod[bi+c][bj+ty]+mod[bj+ty][bi+c]-d[bj+ty]
        const float t1 = sm1[c][ty] + sm2[ty][c] - dJ[ty];
        const int w1 = (int)t1;  const int x1 = w1 < 0 ? -w1 : w1;
        pkT1  |= (w1 & 255) << (8 * k);
        pkTa1 |= (x1 & 255) << (8 * k);
        // A tile (J,I), row ty col c:  mod[bj+ty][bi+c] + mod[bi+c][bj+ty] - d[bi+c]
        const float a2 = sm2[ty][c] + sm1[c][ty] - dI[c];
        const int v2 = (int)a2;  const int u2 = v2 < 0 ? -v2 : v2;
        pkA2  |= (v2 & 255) << (8 * k);
        pkAa2 |= (u2 & 255) << (8 * k);
        // AT tile (I,J), row ty col c: A[bj+c][bi+ty] = mod[bj+c][bi+ty]+mod[bi+ty][bj+c]-d[bi+ty]
        const float t2 = sm2[c][ty] + sm1[ty][c] - dI[ty];
        const int w2 = (int)t2;  const int x2 = w2 < 0 ? -w2 : w2;
        pkT2  |= (w2 & 255) << (8 * k);
        pkTa2 |= (x2 & 255) << (8 * k);
    }
    const size_t oIJ = (size_t)(bi + ty) * N + bj + tx * 4;
    const size_t oJI = (size_t)(bj + ty) * N + bi + tx * 4;
    *(int*)&A  [oIJ] = pkA1;
    *(int*)&Aa [oIJ] = pkAa1;
    *(int*)&AT [oJI] = pkT1;
    *(int*)&ATa[oJI] = pkTa1;
    if (I != J) {
        *(int*)&A  [oJI] = pkA2;
        *(int*)&Aa [oJI] = pkAa2;
        *(int*)&AT [oIJ] = pkT2;
        *(int*)&ATa[oIJ] = pkTa2;
    }
}

// ---------------- kernel 4: i8 GEMM-trace, 256x256 tile, ONE barrier per K-tile -------
// (unchanged from previous round — 122 us, MfmaUtil 46%)
#define BK 64
#define NT (N / BK)      // 64 K-tiles
#define BUFSZ 32768      // A 16K + B 16K per buffer

__global__ __launch_bounds__(512, 2) void gemm_trace_i8(
        const signed char* __restrict__ Ag,
        const signed char* __restrict__ ATg,
        const signed char* __restrict__ Aag,
        const signed char* __restrict__ ATag,
        double* __restrict__ accs) {
    __shared__ __align__(16) signed char lds[4 * BUFSZ];   // 128 KiB
    __shared__ int red[8];
    const int z = blockIdx.z;
    const signed char* Asrc = z ? Aag  : Ag;    // M rows   (i-panel)
    const signed char* Bsrc = z ? ATag : ATg;   // MT rows  (k-panel), B[k][n] = MT[n][k]
    const int i0 = blockIdx.y * 256;
    const int k0 = blockIdx.x * 256;
    const int t = threadIdx.x;
    const int lane = t & 63;
    const int wave = t >> 6;        // 0..7
    const int wm = wave >> 2;       // 0..1 -> M offset wm*128
    const int wn = wave & 3;        // 0..3 -> N offset wn*64
    const int quad = lane >> 4;
    const int col  = lane & 15;

    const int c1 = t;
    const int r1 = c1 >> 2;          // 0..127
    const int r2 = r1 + 128;
    const int s1 = (((c1 & 3) ^ ((r1 >> 1) & 3)) << 4);
    const int s2 = (((c1 & 3) ^ ((r2 >> 1) & 3)) << 4);
    const signed char* gA1 = Asrc + (size_t)(i0 + r1) * N + s1;
    const signed char* gA2 = Asrc + (size_t)(i0 + r2) * N + s2;
    const signed char* gB1 = Bsrc + (size_t)(k0 + r1) * N + s1;
    const signed char* gB2 = Bsrc + (size_t)(k0 + r2) * N + s2;
    const int ldsA1 = (wave * 64) * 16;           // wave-uniform LDS bases
    const int ldsA2 = 8192  + (wave * 64) * 16;
    const int ldsB1 = 16384 + (wave * 64) * 16;
    const int ldsB2 = 24576 + (wave * 64) * 16;
    const int fsw = ((quad ^ ((col >> 1) & 3)) << 4);  // fragment k-slot after swizzle

    int4v acc[8][4];
    #pragma unroll
    for (int a = 0; a < 8; ++a)
        #pragma unroll
        for (int b = 0; b < 4; ++b)
            acc[a][b] = (int4v){0, 0, 0, 0};

    for (int p = 0; p < 3; ++p) {
        const int pb = p * BUFSZ;
        const size_t go = (size_t)p * BK;
        async16(gA1 + go, lds + pb + ldsA1);
        async16(gA2 + go, lds + pb + ldsA2);
        async16(gB1 + go, lds + pb + ldsB1);
        async16(gB2 + go, lds + pb + ldsB2);
    }
    asm volatile("s_waitcnt vmcnt(8)" ::: "memory");
    __builtin_amdgcn_s_barrier();
    __builtin_amdgcn_sched_barrier(0);

    for (int j = 0; j < NT; ++j) {
        const int buf = (j & 3) * BUFSZ;
        const signed char* Ab = lds + buf;
        const signed char* Bb = lds + buf + 16384;
        const int pre = j + 3;
        const size_t go = (size_t)pre * BK;
        const int pb = (pre & 3) * BUFSZ;
        int4v af0[4], af1[4], bf[4];
        #pragma unroll
        for (int tr = 0; tr < 4; ++tr)
            af0[tr] = *(const int4v*)(Ab + ((wm * 128 + tr * 16 + col) << 6) + fsw);
        #pragma unroll
        for (int tc = 0; tc < 4; ++tc)
            bf[tc] = *(const int4v*)(Bb + ((wn * 64 + tc * 16 + col) << 6) + fsw);
        #pragma unroll
        for (int tr = 0; tr < 4; ++tr)
            af1[tr] = *(const int4v*)(Ab + ((wm * 128 + 64 + tr * 16 + col) << 6) + fsw);
        if (pre < NT) {
            async16(gA1 + go, lds + pb + ldsA1);
            async16(gA2 + go, lds + pb + ldsA2);
            async16(gB1 + go, lds + pb + ldsB1);
            async16(gB2 + go, lds + pb + ldsB2);
        }
        asm volatile("s_waitcnt lgkmcnt(4)" ::: "memory");
        __builtin_amdgcn_sched_barrier(0);
        __builtin_amdgcn_s_setprio(1);
        #pragma unroll
        for (int tr = 0; tr < 4; ++tr)
            #pragma unroll
            for (int tc = 0; tc < 4; ++tc)
                acc[tr][tc] = __builtin_amdgcn_mfma_i32_16x16x64_i8(af0[tr], bf[tc], acc[tr][tc], 0, 0, 0);
        __builtin_amdgcn_s_setprio(0);
        asm volatile("s_waitcnt lgkmcnt(0)" ::: "memory");
        __builtin_amdgcn_sched_barrier(0);
        __builtin_amdgcn_s_setprio(1);
        #pragma unroll
        for (int tr = 0; tr < 4; ++tr)
            #pragma unroll
            for (int tc = 0; tc < 4; ++tc)
                acc[4 + tr][tc] = __builtin_amdgcn_mfma_i32_16x16x64_i8(af1[tr], bf[tc], acc[4 + tr][tc], 0, 0, 0);
        __builtin_amdgcn_s_setprio(0);
        if (j < NT - 3)       { asm volatile("s_waitcnt vmcnt(8)" ::: "memory"); }
        else if (j == NT - 3) { asm volatile("s_waitcnt vmcnt(4)" ::: "memory"); }
        else if (j == NT - 2) { asm volatile("s_waitcnt vmcnt(0)" ::: "memory"); }
        __builtin_amdgcn_s_barrier();
        __builtin_amdgcn_sched_barrier(0);
    }

    int part = 0;
    #pragma unroll
    for (int mr = 0; mr < 8; ++mr) {
        const int ib = i0 + wm * 128 + mr * 16 + quad * 4;
        #pragma unroll
        for (int tc = 0; tc < 4; ++tc) {
            const int kk = k0 + wn * 64 + tc * 16 + col;
            const int mv = *(const int*)&Asrc[(size_t)kk * N + ib];
            #pragma unroll
            for (int r = 0; r < 4; ++r)
                part += acc[mr][tc][r] * (int)(signed char)(mv >> (8 * r));
        }
    }
    #pragma unroll
    for (int off = 32; off > 0; off >>= 1)
        part += __shfl_down(part, off, 64);
    if (lane == 0) red[wave] = part;
    __syncthreads();
    if (t == 0) {
        int tot = 0;
        #pragma unroll
        for (int w = 0; w < 8; ++w) tot += red[w];
        atomicAdd(&accs[z], (double)tot);
    }
}

// ---------------- kernel 5: balance ----------------
__global__ void finalize_kernel(const double* __restrict__ accs, float* __restrict__ out) {
    out[NN] = (float)(0.5 * (1.0 + accs[0] / accs[1]));
}

extern "C" void kernel_launch(void* const* d_in, const int* in_sizes, int n_in,
                              void* d_out, int out_size, void* d_ws, size_t ws_size,
                              hipStream_t stream) {
    const float* ori = (const float*)d_in[0];
    const float* clp = (const float*)d_in[1];
    const float* u   = (const float*)d_in[2];
    float* out = (float*)d_out;
    char* ws = (char*)d_ws;
    signed char* A8   = (signed char*)ws;                    // 16 MiB
    signed char* AT8  = (signed char*)(ws + NN);             // 16 MiB
    signed char* Aa8  = (signed char*)(ws + 2 * NN);         // 16 MiB
    signed char* ATa8 = (signed char*)(ws + 3 * NN);         // 16 MiB
    double*      accs = (double*)(ws + 4 * NN);              // 16 B

    fused_mod_build<<<dim3(128, 128), dim3(8, 32), 0, stream>>>(
        ori, clp, u, out, A8, AT8, Aa8, ATa8, accs);
    gemm_trace_i8<<<dim3(N / 256, N / 256, 2), 512, 0, stream>>>(A8, AT8, Aa8, ATa8, accs);
    finalize_kernel<<<1, 1, 0, stream>>>(accs, out);
}